// Round 7
// baseline (57.436 us; speedup 1.0000x reference)
//
#include <hip/hip_runtime.h>

// Reference collapses: softmax over a singleton axis == 1, so
//   out[b,c,:,:] = (Wout @ v_b + bout)[c],  v_b = Wkv[C:,:] @ context[b]
// x and Wq are dead. Bound by the 134 MB output write.
//
// SINGLE kernel (R6 post-mortem: ~12 us of the 33 was GEMV walls + 2 kernel
// boundaries). 256 blocks x 512 threads; block owns 32 consecutive rows of
// one batch b. Phase A: redundantly compute v[b,:] per block (512 KB Wkv
// panel, L2-resident across the 16 blocks/batch). Phase B: 32 y-dots.
// Phase C: pure broadcast stores (proven saturating shape).

#define BB   16
#define CC   512
#define CTX  256
#define NN   4096   // H*W

typedef float f32x4 __attribute__((ext_vector_type(4)));

__global__ __launch_bounds__(512) void fused_kernel(
    const float* __restrict__ ctx,   // B x CTX
    const float* __restrict__ Wkv,   // 2C x CTX
    const float* __restrict__ Wout,  // C x C
    const float* __restrict__ bout,  // C
    f32x4* __restrict__ out)         // B*C*NN floats
{
    __shared__ float v_s[CC];
    __shared__ float y_s[32];

    const int wave = threadIdx.x >> 6;          // 0..7
    const int lane = threadIdx.x & 63;
    const int blk  = blockIdx.x;                // 0..255
    const int b    = blk >> 4;                  // 16 blocks per batch
    const int r0   = blk << 5;                  // first global row (b*CC + c0)
    const int c0   = (blk & 15) << 5;           // first channel of this block

    // context fragment: 64 lanes x f32x4 = the whole 256-float row
    const f32x4 cx = ((const f32x4*)(ctx + b * CTX))[lane];

    // Phase A: v[b, j], j = wave*64 .. +63. Wave streams 64 KB of Wkv.
    const int j0 = wave << 6;
    #pragma unroll 4
    for (int jj = 0; jj < 64; ++jj) {
        const int j = j0 + jj;
        const f32x4 wv = ((const f32x4*)(Wkv + (size_t)(CC + j) * CTX))[lane];
        float p = wv.x * cx.x + wv.y * cx.y + wv.z * cx.z + wv.w * cx.w;
        #pragma unroll
        for (int m = 32; m >= 1; m >>= 1) p += __shfl_xor(p, m);
        if (lane == 0) v_s[j] = p;
    }
    __syncthreads();

    // Phase B: y for the block's 32 channels; wave handles 4.
    const f32x4* vr = (const f32x4*)v_s;
    #pragma unroll
    for (int i = 0; i < 4; ++i) {
        const int cl = (wave << 2) + i;         // 0..31
        const int c  = c0 + cl;
        const f32x4* wr = (const f32x4*)(Wout + (size_t)c * CC);
        const f32x4 w0 = wr[lane],      v0 = vr[lane];
        const f32x4 w1 = wr[64 + lane], v1 = vr[64 + lane];
        float p = w0.x * v0.x + w0.y * v0.y + w0.z * v0.z + w0.w * v0.w
                + w1.x * v1.x + w1.y * v1.y + w1.z * v1.z + w1.w * v1.w;
        #pragma unroll
        for (int m = 32; m >= 1; m >>= 1) p += __shfl_xor(p, m);
        if (lane == 0) y_s[cl] = p + bout[c];
    }
    __syncthreads();

    // Phase C: broadcast stores; wave owns 4 rows x 16 KB.
    #pragma unroll
    for (int i = 0; i < 4; ++i) {
        const int cl = (wave << 2) + i;
        const float yv = y_s[cl];
        f32x4 val; val.x = yv; val.y = yv; val.z = yv; val.w = yv;
        f32x4* dst = out + (size_t)(r0 + cl) * (NN / 4) + lane;
        #pragma unroll
        for (int j = 0; j < 16; ++j)
            dst[j * 64] = val;
    }
}

extern "C" void kernel_launch(void* const* d_in, const int* in_sizes, int n_in,
                              void* d_out, int out_size, void* d_ws, size_t ws_size,
                              hipStream_t stream) {
    // inputs: 0=x (dead), 1=context, 2=Wq (dead), 3=Wkv, 4=Wout, 5=bout
    const float* context = (const float*)d_in[1];
    const float* Wkv     = (const float*)d_in[3];
    const float* Wout    = (const float*)d_in[4];
    const float* bout    = (const float*)d_in[5];
    f32x4* out = (f32x4*)d_out;

    fused_kernel<<<256, 512, 0, stream>>>(context, Wkv, Wout, bout, out);
}